// Round 4
// baseline (224.144 us; speedup 1.0000x reference)
//
#include <hip/hip_runtime.h>
#include <stdint.h>

typedef __attribute__((ext_vector_type(4))) float f32x4;
typedef __attribute__((ext_vector_type(8))) short bf16x8;
typedef __attribute__((ext_vector_type(4))) unsigned short u16x4;

constexpr int cB = 4, cS = 4096, cD = 1024, cH = 1024;
constexpr int cM = cB * cS;      // 16384
constexpr int cN = 2 * cH;       // 2048
constexpr int cK = cD;           // 1024
constexpr int NCH = 64;          // scan chunks along S
constexpr int CLEN = cS / NCH;   // 64

__device__ __forceinline__ unsigned short f2bf(float f) {
  union { float f; uint32_t u; } v; v.f = f;
  uint32_t r = v.u + 0x7FFFu + ((v.u >> 16) & 1u);
  return (unsigned short)(r >> 16);
}
__device__ __forceinline__ float bf2f(unsigned short h) {
  union { float f; uint32_t u; } v; v.u = ((uint32_t)h) << 16;
  return v.f;
}

__global__ void round_kernel(const float* __restrict__ src,
                             unsigned short* __restrict__ hi) {
  int i = (blockIdx.x * blockDim.x + threadIdx.x) * 4;
  f32x4 x = *(const f32x4*)(src + i);
  u16x4 h;
#pragma unroll
  for (int j = 0; j < 4; ++j) h[j] = f2bf(x[j]);
  *(u16x4*)(hi + i) = h;
}

__global__ void split_kernel(const float* __restrict__ src,
                             unsigned short* __restrict__ hi,
                             unsigned short* __restrict__ lo) {
  int i = (blockIdx.x * blockDim.x + threadIdx.x) * 4;
  f32x4 x = *(const f32x4*)(src + i);
  u16x4 h, l;
#pragma unroll
  for (int j = 0; j < 4; ++j) {
    unsigned short hb = f2bf(x[j]);
    h[j] = hb;
    l[j] = f2bf(x[j] - bf2f(hb));
  }
  *(u16x4*)(hi + i) = h;
  *(u16x4*)(lo + i) = l;
}

// =================== pipelined GEMM: [16384 x 2048] = x_bf * (W_hi + W_lo)^T ==
constexpr int BM = 256, BN = 128, BK = 64;
constexpr int NT = cK / BK;   // 16 K-tiles

#define BARRIER() asm volatile("s_barrier" ::: "memory")
#define WAITVM2() asm volatile("s_waitcnt vmcnt(2)" ::: "memory")
#define WAITVM0() asm volatile("s_waitcnt vmcnt(0)" ::: "memory")

// stage 64 rows x 64 cols bf16 (8 KiB) with pre-swizzled source (rule #21)
__device__ __forceinline__ void stage64(const unsigned short* __restrict__ g,
                                        unsigned short* lds, int tid) {
  const int srow = tid >> 3;                       // 0..63
  const int scol = ((tid & 7) ^ (srow & 7)) << 3;  // swizzled 16B slot
  __builtin_amdgcn_global_load_lds(
      (const __attribute__((address_space(1))) void*)(g + (size_t)srow * cK + scol),
      (__attribute__((address_space(3))) void*)(lds + (size_t)tid * 8), 16, 0, 0);
}
// stage 128 rows (one "unit" = 2 global_load_lds per wave)
__device__ __forceinline__ void stage128(const unsigned short* __restrict__ g,
                                         unsigned short* lds, int tid) {
  stage64(g, lds, tid);
  stage64(g + (size_t)64 * cK, lds + 4096, tid);
}

__global__ __launch_bounds__(512, 2) void gemm_kernel(
    const unsigned short* __restrict__ xh,
    const unsigned short* __restrict__ wwh, const unsigned short* __restrict__ wwl,
    const float* __restrict__ bz, const float* __restrict__ bhv,
    unsigned short* __restrict__ cbuf, unsigned short* __restrict__ gbuf)
{
  __shared__ unsigned short Ab[2][BM * BK];   // 2 x 32 KiB
  __shared__ unsigned short Bh[2][BN * BK];   // 2 x 16 KiB
  __shared__ unsigned short Bl[2][BN * BK];   // 2 x 16 KiB  (total 128 KiB)

  const int tid = threadIdx.x;
  const int lane = tid & 63;
  const int wv = tid >> 6;            // 0..7
  const int wr = wv >> 1, wc = wv & 1;
  const int fr = lane & 15, fq = lane >> 4;

  // XCD-aware swizzle: nwg=1024, divisible by 8 -> simple bijective form
  const int bid = blockIdx.x;
  const int swz = (bid & 7) * 128 + (bid >> 3);
  const int mt = swz >> 4, nt = swz & 15;
  const int m0 = mt * BM, n0 = nt * BN;

  f32x4 acc[4][4] = {};

  const unsigned short* gA0 = xh + (size_t)m0 * cK;
  const unsigned short* gA1 = xh + (size_t)(m0 + 128) * cK;
  const unsigned short* gBh = wwh + (size_t)n0 * cK;
  const unsigned short* gBl = wwl + (size_t)n0 * cK;

  // prologue: stage tile 0 into buf 0 (order A0,A1,Bh,Bl = 8 loads/wave)
  stage128(gA0, Ab[0], tid);
  stage128(gA1, Ab[0] + 8192, tid);
  stage128(gBh, Bh[0], tid);
  stage128(gBl, Bl[0], tid);
  WAITVM2();   // A0,A1,Bh landed; Bl may be in flight
  BARRIER();

#pragma unroll 2
  for (int t = 0; t < NT; ++t) {
    const int cur = t & 1, nxt = cur ^ 1;
    const int kn = (t + 1) * BK;
    const unsigned short* A  = Ab[cur];
    const unsigned short* BHc = Bh[cur];
    const unsigned short* BLc = Bl[cur];
    const bool more = (t + 1 < NT);

    bf16x8 fa0[4], fbh0[4], fbl0[4], fa1[4], fbh1[4], fbl1[4];

    // ---- phase 0: read A(kk0)+Bh(kk0); stage A0(t+1); MFMA fa0*fbh0
#pragma unroll
    for (int i = 0; i < 4; ++i) {
      const int r = wr * 64 + i * 16 + fr;
      fa0[i] = *(const bf16x8*)(A + r * 64 + ((fq ^ (r & 7)) << 3));
    }
#pragma unroll
    for (int j = 0; j < 4; ++j) {
      const int r = wc * 64 + j * 16 + fr;
      fbh0[j] = *(const bf16x8*)(BHc + r * 64 + ((fq ^ (r & 7)) << 3));
    }
    if (more) stage128(gA0 + kn, Ab[nxt], tid);
    BARRIER();
    __builtin_amdgcn_s_setprio(1);
#pragma unroll
    for (int i = 0; i < 4; ++i)
#pragma unroll
      for (int j = 0; j < 4; ++j)
        acc[i][j] = __builtin_amdgcn_mfma_f32_16x16x32_bf16(fa0[i], fbh0[j], acc[i][j], 0, 0, 0);
    __builtin_amdgcn_s_setprio(0);
    if (more) { WAITVM2(); } else { WAITVM0(); }   // Bl(t) landed
    BARRIER();

    // ---- phase 1: read Bl(kk0); stage A1(t+1); MFMA fa0*fbl0
#pragma unroll
    for (int j = 0; j < 4; ++j) {
      const int r = wc * 64 + j * 16 + fr;
      fbl0[j] = *(const bf16x8*)(BLc + r * 64 + ((fq ^ (r & 7)) << 3));
    }
    if (more) stage128(gA1 + kn, Ab[nxt] + 8192, tid);
    BARRIER();
    __builtin_amdgcn_s_setprio(1);
#pragma unroll
    for (int i = 0; i < 4; ++i)
#pragma unroll
      for (int j = 0; j < 4; ++j)
        acc[i][j] = __builtin_amdgcn_mfma_f32_16x16x32_bf16(fa0[i], fbl0[j], acc[i][j], 0, 0, 0);
    __builtin_amdgcn_s_setprio(0);
    BARRIER();

    // ---- phase 2: read A(kk1)+Bh(kk1); stage Bh(t+1); MFMA fa1*fbh1
#pragma unroll
    for (int i = 0; i < 4; ++i) {
      const int r = wr * 64 + i * 16 + fr;
      fa1[i] = *(const bf16x8*)(A + r * 64 + (((4 + fq) ^ (r & 7)) << 3));
    }
#pragma unroll
    for (int j = 0; j < 4; ++j) {
      const int r = wc * 64 + j * 16 + fr;
      fbh1[j] = *(const bf16x8*)(BHc + r * 64 + (((4 + fq) ^ (r & 7)) << 3));
    }
    if (more) stage128(gBh + kn, Bh[nxt], tid);
    BARRIER();
    __builtin_amdgcn_s_setprio(1);
#pragma unroll
    for (int i = 0; i < 4; ++i)
#pragma unroll
      for (int j = 0; j < 4; ++j)
        acc[i][j] = __builtin_amdgcn_mfma_f32_16x16x32_bf16(fa1[i], fbh1[j], acc[i][j], 0, 0, 0);
    __builtin_amdgcn_s_setprio(0);
    BARRIER();

    // ---- phase 3: read Bl(kk1); stage Bl(t+1); MFMA fa1*fbl1
#pragma unroll
    for (int j = 0; j < 4; ++j) {
      const int r = wc * 64 + j * 16 + fr;
      fbl1[j] = *(const bf16x8*)(BLc + r * 64 + (((4 + fq) ^ (r & 7)) << 3));
    }
    if (more) stage128(gBl + kn, Bl[nxt], tid);
    BARRIER();
    __builtin_amdgcn_s_setprio(1);
#pragma unroll
    for (int i = 0; i < 4; ++i)
#pragma unroll
      for (int j = 0; j < 4; ++j)
        acc[i][j] = __builtin_amdgcn_mfma_f32_16x16x32_bf16(fa1[i], fbl1[j], acc[i][j], 0, 0, 0);
    __builtin_amdgcn_s_setprio(0);
    if (more) { WAITVM2(); }   // A0,A1,Bh(t+1) landed; Bl(t+1) in flight
    BARRIER();
  }

  // epilogue: n<1024 -> c = sigmoid(-k); else g = a>=0 ? a+0.5 : sigmoid(a); bf16 out
  const bool is_k = (n0 < cH);
#pragma unroll
  for (int j = 0; j < 4; ++j) {
    const int n = n0 + wc * 64 + j * 16 + fr;
    const float bias = is_k ? bz[n] : bhv[n - cH];
#pragma unroll
    for (int i = 0; i < 4; ++i) {
#pragma unroll
      for (int rg = 0; rg < 4; ++rg) {
        const int m = m0 + wr * 64 + i * 16 + fq * 4 + rg;
        const float val = acc[i][j][rg] + bias;
        if (is_k) {
          cbuf[(size_t)m * cH + n] = f2bf(1.0f / (1.0f + expf(val)));
        } else {
          const float g = (val >= 0.0f) ? (val + 0.5f) : (1.0f / (1.0f + expf(-val)));
          gbuf[(size_t)m * cH + (n - cH)] = f2bf(g);
        }
      }
    }
  }
}

// =================== chunked scan: h_t = c_t*h_{t-1} + (1-c_t)*g_t ============
__global__ void scan_chunk_kernel(const unsigned short* __restrict__ cb,
                                  const unsigned short* __restrict__ gb,
                                  float* __restrict__ Pb, float* __restrict__ Qb) {
  const int bc = blockIdx.x;
  const int b = bc / NCH, ch = bc % NCH;
  const int h4 = threadIdx.x * 4;
  size_t base = ((size_t)b * cS + (size_t)ch * CLEN) * cH + h4;
  f32x4 p = {1.f, 1.f, 1.f, 1.f};
  f32x4 q = {0.f, 0.f, 0.f, 0.f};
#pragma unroll 4
  for (int i = 0; i < CLEN; ++i) {
    u16x4 cv = *(const u16x4*)(cb + base + (size_t)i * cH);
    u16x4 gv = *(const u16x4*)(gb + base + (size_t)i * cH);
#pragma unroll
    for (int j = 0; j < 4; ++j) {
      const float c = bf2f(cv[j]), g = bf2f(gv[j]);
      q[j] = c * q[j] + (1.0f - c) * g;
      p[j] *= c;
    }
  }
  size_t o = ((size_t)b * NCH + ch) * cH + h4;
  *(f32x4*)(Pb + o) = p;
  *(f32x4*)(Qb + o) = q;
}

__global__ void scan_prefix_kernel(const float* __restrict__ h0,
                                   const float* __restrict__ Pb, const float* __restrict__ Qb,
                                   float* __restrict__ hin) {
  const int idx = blockIdx.x * blockDim.x + threadIdx.x;  // b*H+h
  const int b = idx / cH, h = idx % cH;
  float x = h0[idx];
  float hc = (x >= 0.0f) ? (x + 0.5f) : (1.0f / (1.0f + expf(-x)));  // g(h0)
#pragma unroll 4
  for (int j = 0; j < NCH; ++j) {
    size_t o = ((size_t)b * NCH + j) * cH + h;
    hin[o] = hc;
    hc = Qb[o] + Pb[o] * hc;
  }
}

__global__ void scan_write_kernel(const unsigned short* __restrict__ cb,
                                  const unsigned short* __restrict__ gb,
                                  const float* __restrict__ hin, float* __restrict__ out) {
  const int bc = blockIdx.x;
  const int b = bc / NCH, ch = bc % NCH;
  const int h4 = threadIdx.x * 4;
  f32x4 hc = *(const f32x4*)(hin + ((size_t)b * NCH + ch) * cH + h4);
  size_t base = ((size_t)b * cS + (size_t)ch * CLEN) * cH + h4;
#pragma unroll 4
  for (int i = 0; i < CLEN; ++i) {
    u16x4 cv = *(const u16x4*)(cb + base + (size_t)i * cH);
    u16x4 gv = *(const u16x4*)(gb + base + (size_t)i * cH);
#pragma unroll
    for (int j = 0; j < 4; ++j) {
      const float c = bf2f(cv[j]), g = bf2f(gv[j]);
      hc[j] = c * hc[j] + (1.0f - c) * g;
    }
    *(f32x4*)(out + base + (size_t)i * cH) = hc;
  }
  if (ch == NCH - 1) {
    *(f32x4*)(out + (size_t)cM * cH + (size_t)b * cH + h4) = hc;
  }
}

extern "C" void kernel_launch(void* const* d_in, const int* in_sizes, int n_in,
                              void* d_out, int out_size, void* d_ws, size_t ws_size,
                              hipStream_t stream) {
  const float* x   = (const float*)d_in[0];
  const float* h0  = (const float*)d_in[1];
  const float* Wz  = (const float*)d_in[2];
  const float* bz  = (const float*)d_in[3];
  const float* Wh  = (const float*)d_in[4];
  const float* bh  = (const float*)d_in[5];

  char* ws = (char*)d_ws;
  unsigned short* xh   = (unsigned short*)(ws);                         // 32 MiB
  unsigned short* wwh  = (unsigned short*)(ws + (((size_t)32) << 20));  // 4 MiB
  unsigned short* wwl  = (unsigned short*)(ws + (((size_t)36) << 20));  // 4 MiB
  unsigned short* cbuf = (unsigned short*)(ws + (((size_t)40) << 20));  // 32 MiB
  unsigned short* gbuf = (unsigned short*)(ws + (((size_t)72) << 20));  // 32 MiB
  float* Pb   = (float*)(ws + (((size_t)104) << 20));                   // 1 MiB
  float* Qb   = (float*)(ws + (((size_t)105) << 20));                   // 1 MiB
  float* hin  = (float*)(ws + (((size_t)106) << 20));                   // 1 MiB
  float* out  = (float*)d_out;

  round_kernel<<<cM * cK / 1024, 256, 0, stream>>>(x, xh);
  split_kernel<<<cH * cK / 1024, 256, 0, stream>>>(Wz, wwh, wwl);
  split_kernel<<<cH * cK / 1024, 256, 0, stream>>>(Wh, wwh + (size_t)cH * cK, wwl + (size_t)cH * cK);
  gemm_kernel<<<(cM / BM) * (cN / BN), 512, 0, stream>>>(xh, wwh, wwl, bz, bh, cbuf, gbuf);
  scan_chunk_kernel<<<cB * NCH, 256, 0, stream>>>(cbuf, gbuf, Pb, Qb);
  scan_prefix_kernel<<<cB * cH / 256, 256, 0, stream>>>(h0, Pb, Qb, hin);
  scan_write_kernel<<<cB * NCH, 256, 0, stream>>>(cbuf, gbuf, hin, out);
}

// Round 5
// 217.786 us; speedup vs baseline: 1.0292x; 1.0292x over previous
//
#include <hip/hip_runtime.h>
#include <stdint.h>

typedef __attribute__((ext_vector_type(4))) float f32x4;
typedef __attribute__((ext_vector_type(8))) short bf16x8;
typedef __attribute__((ext_vector_type(4))) unsigned short u16x4;

constexpr int cB = 4, cS = 4096, cD = 1024, cH = 1024;
constexpr int cM = cB * cS;      // 16384
constexpr int cN = 2 * cH;       // 2048
constexpr int cK = cD;           // 1024
constexpr int NCH = 64;          // scan chunks along S
constexpr int CLEN = cS / NCH;   // 64

__device__ __forceinline__ unsigned short f2bf(float f) {
  union { float f; uint32_t u; } v; v.f = f;
  uint32_t r = v.u + 0x7FFFu + ((v.u >> 16) & 1u);
  return (unsigned short)(r >> 16);
}
__device__ __forceinline__ float bf2f(unsigned short h) {
  union { float f; uint32_t u; } v; v.u = ((uint32_t)h) << 16;
  return v.f;
}

__global__ void round_kernel(const float* __restrict__ src,
                             unsigned short* __restrict__ hi) {
  int i = (blockIdx.x * blockDim.x + threadIdx.x) * 4;
  f32x4 x = *(const f32x4*)(src + i);
  u16x4 h;
#pragma unroll
  for (int j = 0; j < 4; ++j) h[j] = f2bf(x[j]);
  *(u16x4*)(hi + i) = h;
}

__global__ void split_kernel(const float* __restrict__ src,
                             unsigned short* __restrict__ hi,
                             unsigned short* __restrict__ lo) {
  int i = (blockIdx.x * blockDim.x + threadIdx.x) * 4;
  f32x4 x = *(const f32x4*)(src + i);
  u16x4 h, l;
#pragma unroll
  for (int j = 0; j < 4; ++j) {
    unsigned short hb = f2bf(x[j]);
    h[j] = hb;
    l[j] = f2bf(x[j] - bf2f(hb));
  }
  *(u16x4*)(hi + i) = h;
  *(u16x4*)(lo + i) = l;
}

// =================== pipelined GEMM: [16384 x 2048] = x_bf * (W_hi + W_lo)^T ==
constexpr int BM = 256, BN = 128, BK = 64;
constexpr int NT = cK / BK;   // 16 K-tiles

#define BARRIER() asm volatile("s_barrier" ::: "memory")
#define WAITVM4() asm volatile("s_waitcnt vmcnt(4)" ::: "memory")
#define WAITVM2() asm volatile("s_waitcnt vmcnt(2)" ::: "memory")
#define WAITVM0() asm volatile("s_waitcnt vmcnt(0)" ::: "memory")

// stage 64 rows x 64 cols bf16 (8 KiB) with pre-swizzled source (rule #21)
__device__ __forceinline__ void stage64(const unsigned short* __restrict__ g,
                                        unsigned short* lds, int tid) {
  const int srow = tid >> 3;                       // 0..63
  const int scol = ((tid & 7) ^ (srow & 7)) << 3;  // swizzled 16B slot
  __builtin_amdgcn_global_load_lds(
      (const __attribute__((address_space(1))) void*)(g + (size_t)srow * cK + scol),
      (__attribute__((address_space(3))) void*)(lds + (size_t)tid * 8), 16, 0, 0);
}
// stage 128 rows (2 global_load_lds per wave)
__device__ __forceinline__ void stage128(const unsigned short* __restrict__ g,
                                         unsigned short* lds, int tid) {
  stage64(g, lds, tid);
  stage64(g + (size_t)64 * cK, lds + 4096, tid);
}

__global__ __launch_bounds__(512, 2) void gemm_kernel(
    const unsigned short* __restrict__ xh,
    const unsigned short* __restrict__ wwh, const unsigned short* __restrict__ wwl,
    const float* __restrict__ bz, const float* __restrict__ bhv,
    unsigned short* __restrict__ cbuf, unsigned short* __restrict__ gbuf)
{
  __shared__ unsigned short Ab[2][BM * BK];   // 2 x 32 KiB
  __shared__ unsigned short Bh[2][BN * BK];   // 2 x 16 KiB
  __shared__ unsigned short Bl[2][BN * BK];   // 2 x 16 KiB  (total 128 KiB)

  const int tid = threadIdx.x;
  const int lane = tid & 63;
  const int wv = tid >> 6;            // 0..7
  const int wr = wv >> 1, wc = wv & 1;
  const int fr = lane & 15, fq = lane >> 4;

  // XCD-aware swizzle: nwg=1024, divisible by 8 -> bijective
  const int bid = blockIdx.x;
  const int swz = (bid & 7) * 128 + (bid >> 3);
  const int mt = swz >> 4, nt = swz & 15;
  const int m0 = mt * BM, n0 = nt * BN;

  f32x4 acc[4][4] = {};

  const unsigned short* gA0 = xh + (size_t)m0 * cK;
  const unsigned short* gA1 = xh + (size_t)(m0 + 128) * cK;
  const unsigned short* gBh = wwh + (size_t)n0 * cK;
  const unsigned short* gBl = wwl + (size_t)n0 * cK;

  // prologue: stage tile 0 (order: A0,A1,Bh,Bl = 8 loads/wave)
  stage128(gA0, Ab[0], tid);
  stage128(gA1, Ab[0] + 8192, tid);
  stage128(gBh, Bh[0], tid);
  stage128(gBl, Bl[0], tid);
  WAITVM2();   // A0,A1,Bh landed; own Bl may be in flight
  BARRIER();   // tile-0 A/Bh globally visible

#pragma unroll 2
  for (int t = 0; t < NT; ++t) {
    const int cur = t & 1, nxt = cur ^ 1;
    const int kn = (t + 1) * BK;
    const unsigned short* A   = Ab[cur];
    const unsigned short* BHc = Bh[cur];
    const unsigned short* BLc = Bl[cur];
    const bool more = (t + 1 < NT);

    bf16x8 fa[2][4], fbh[2][4], fbl[2][4];

    // ======== half 1: read ALL fa+fbh (16 ds_read); stage A(t+1); 32 MFMA
#pragma unroll
    for (int kk = 0; kk < 2; ++kk)
#pragma unroll
      for (int i = 0; i < 4; ++i) {
        const int r = wr * 64 + i * 16 + fr;
        fa[kk][i] = *(const bf16x8*)(A + r * 64 + (((kk * 4 + fq) ^ (r & 7)) << 3));
      }
#pragma unroll
    for (int kk = 0; kk < 2; ++kk)
#pragma unroll
      for (int j = 0; j < 4; ++j) {
        const int r = wc * 64 + j * 16 + fr;
        fbh[kk][j] = *(const bf16x8*)(BHc + r * 64 + (((kk * 4 + fq) ^ (r & 7)) << 3));
      }
    if (more) { stage128(gA0 + kn, Ab[nxt], tid); stage128(gA1 + kn, Ab[nxt] + 8192, tid); }
    __builtin_amdgcn_s_setprio(1);
#pragma unroll
    for (int kk = 0; kk < 2; ++kk)
#pragma unroll
      for (int i = 0; i < 4; ++i)
#pragma unroll
        for (int j = 0; j < 4; ++j)
          acc[i][j] = __builtin_amdgcn_mfma_f32_16x16x32_bf16(fa[kk][i], fbh[kk][j], acc[i][j], 0, 0, 0);
    __builtin_amdgcn_s_setprio(0);
    // drain own Bl(t): outstanding = Bl(t):2 [+ A(t+1):4 if more]
    if (more) { WAITVM4(); } else { WAITVM0(); }
    BARRIER();   // all waves' Bl(t) visible

    // ======== half 2: read fbl (8 ds_read); stage Bh,Bl(t+1); 32 MFMA
#pragma unroll
    for (int kk = 0; kk < 2; ++kk)
#pragma unroll
      for (int j = 0; j < 4; ++j) {
        const int r = wc * 64 + j * 16 + fr;
        fbl[kk][j] = *(const bf16x8*)(BLc + r * 64 + (((kk * 4 + fq) ^ (r & 7)) << 3));
      }
    if (more) { stage128(gBh + kn, Bh[nxt], tid); stage128(gBl + kn, Bl[nxt], tid); }
    __builtin_amdgcn_s_setprio(1);
#pragma unroll
    for (int kk = 0; kk < 2; ++kk)
#pragma unroll
      for (int i = 0; i < 4; ++i)
#pragma unroll
        for (int j = 0; j < 4; ++j)
          acc[i][j] = __builtin_amdgcn_mfma_f32_16x16x32_bf16(fa[kk][i], fbl[kk][j], acc[i][j], 0, 0, 0);
    __builtin_amdgcn_s_setprio(0);
    // drain A0,A1,Bh(t+1), leave Bl(t+1) in flight
    if (more) { WAITVM2(); }
    BARRIER();   // tile t+1 A/Bh globally visible
  }

  // epilogue: n<1024 -> c = sigmoid(-k); else g = a>=0 ? a+0.5 : sigmoid(a); bf16 out
  const bool is_k = (n0 < cH);
#pragma unroll
  for (int j = 0; j < 4; ++j) {
    const int n = n0 + wc * 64 + j * 16 + fr;
    const float bias = is_k ? bz[n] : bhv[n - cH];
#pragma unroll
    for (int i = 0; i < 4; ++i) {
#pragma unroll
      for (int rg = 0; rg < 4; ++rg) {
        const int m = m0 + wr * 64 + i * 16 + fq * 4 + rg;
        const float val = acc[i][j][rg] + bias;
        if (is_k) {
          cbuf[(size_t)m * cH + n] = f2bf(1.0f / (1.0f + expf(val)));
        } else {
          const float g = (val >= 0.0f) ? (val + 0.5f) : (1.0f / (1.0f + expf(-val)));
          gbuf[(size_t)m * cH + (n - cH)] = f2bf(g);
        }
      }
    }
  }
}

// =================== chunked scan: h_t = c_t*h_{t-1} + (1-c_t)*g_t ============
__global__ void scan_chunk_kernel(const unsigned short* __restrict__ cb,
                                  const unsigned short* __restrict__ gb,
                                  float* __restrict__ Pb, float* __restrict__ Qb) {
  const int bc = blockIdx.x;
  const int b = bc / NCH, ch = bc % NCH;
  const int h4 = threadIdx.x * 4;
  size_t base = ((size_t)b * cS + (size_t)ch * CLEN) * cH + h4;
  f32x4 p = {1.f, 1.f, 1.f, 1.f};
  f32x4 q = {0.f, 0.f, 0.f, 0.f};
#pragma unroll 4
  for (int i = 0; i < CLEN; ++i) {
    u16x4 cv = *(const u16x4*)(cb + base + (size_t)i * cH);
    u16x4 gv = *(const u16x4*)(gb + base + (size_t)i * cH);
#pragma unroll
    for (int j = 0; j < 4; ++j) {
      const float c = bf2f(cv[j]), g = bf2f(gv[j]);
      q[j] = c * q[j] + (1.0f - c) * g;
      p[j] *= c;
    }
  }
  size_t o = ((size_t)b * NCH + ch) * cH + h4;
  *(f32x4*)(Pb + o) = p;
  *(f32x4*)(Qb + o) = q;
}

__global__ void scan_prefix_kernel(const float* __restrict__ h0,
                                   const float* __restrict__ Pb, const float* __restrict__ Qb,
                                   float* __restrict__ hin) {
  const int idx = blockIdx.x * blockDim.x + threadIdx.x;  // b*H+h
  const int b = idx / cH, h = idx % cH;
  float x = h0[idx];
  float hc = (x >= 0.0f) ? (x + 0.5f) : (1.0f / (1.0f + expf(-x)));  // g(h0)
#pragma unroll 4
  for (int j = 0; j < NCH; ++j) {
    size_t o = ((size_t)b * NCH + j) * cH + h;
    hin[o] = hc;
    hc = Qb[o] + Pb[o] * hc;
  }
}

__global__ void scan_write_kernel(const unsigned short* __restrict__ cb,
                                  const unsigned short* __restrict__ gb,
                                  const float* __restrict__ hin, float* __restrict__ out) {
  const int bc = blockIdx.x;
  const int b = bc / NCH, ch = bc % NCH;
  const int h4 = threadIdx.x * 4;
  f32x4 hc = *(const f32x4*)(hin + ((size_t)b * NCH + ch) * cH + h4);
  size_t base = ((size_t)b * cS + (size_t)ch * CLEN) * cH + h4;
#pragma unroll 4
  for (int i = 0; i < CLEN; ++i) {
    u16x4 cv = *(const u16x4*)(cb + base + (size_t)i * cH);
    u16x4 gv = *(const u16x4*)(gb + base + (size_t)i * cH);
#pragma unroll
    for (int j = 0; j < 4; ++j) {
      const float c = bf2f(cv[j]), g = bf2f(gv[j]);
      hc[j] = c * hc[j] + (1.0f - c) * g;
    }
    *(f32x4*)(out + base + (size_t)i * cH) = hc;
  }
  if (ch == NCH - 1) {
    *(f32x4*)(out + (size_t)cM * cH + (size_t)b * cH + h4) = hc;
  }
}

extern "C" void kernel_launch(void* const* d_in, const int* in_sizes, int n_in,
                              void* d_out, int out_size, void* d_ws, size_t ws_size,
                              hipStream_t stream) {
  const float* x   = (const float*)d_in[0];
  const float* h0  = (const float*)d_in[1];
  const float* Wz  = (const float*)d_in[2];
  const float* bz  = (const float*)d_in[3];
  const float* Wh  = (const float*)d_in[4];
  const float* bh  = (const float*)d_in[5];

  char* ws = (char*)d_ws;
  unsigned short* xh   = (unsigned short*)(ws);                         // 32 MiB
  unsigned short* wwh  = (unsigned short*)(ws + (((size_t)32) << 20));  // 4 MiB
  unsigned short* wwl  = (unsigned short*)(ws + (((size_t)36) << 20));  // 4 MiB
  unsigned short* cbuf = (unsigned short*)(ws + (((size_t)40) << 20));  // 32 MiB
  unsigned short* gbuf = (unsigned short*)(ws + (((size_t)72) << 20));  // 32 MiB
  float* Pb   = (float*)(ws + (((size_t)104) << 20));                   // 1 MiB
  float* Qb   = (float*)(ws + (((size_t)105) << 20));                   // 1 MiB
  float* hin  = (float*)(ws + (((size_t)106) << 20));                   // 1 MiB
  float* out  = (float*)d_out;

  round_kernel<<<cM * cK / 1024, 256, 0, stream>>>(x, xh);
  split_kernel<<<cH * cK / 1024, 256, 0, stream>>>(Wz, wwh, wwl);
  split_kernel<<<cH * cK / 1024, 256, 0, stream>>>(Wh, wwh + (size_t)cH * cK, wwl + (size_t)cH * cK);
  gemm_kernel<<<(cM / BM) * (cN / BN), 512, 0, stream>>>(xh, wwh, wwl, bz, bh, cbuf, gbuf);
  scan_chunk_kernel<<<cB * NCH, 256, 0, stream>>>(cbuf, gbuf, Pb, Qb);
  scan_prefix_kernel<<<cB * cH / 256, 256, 0, stream>>>(h0, Pb, Qb, hin);
  scan_write_kernel<<<cB * NCH, 256, 0, stream>>>(cbuf, gbuf, hin, out);
}